// Round 19
// baseline (335.363 us; speedup 1.0000x reference)
//
#include <hip/hip_runtime.h>
#include <hip/hip_bf16.h>

typedef unsigned short u16;
typedef __attribute__((ext_vector_type(4))) float f32x4;
typedef __attribute__((ext_vector_type(8))) short bf16x8;

typedef const __attribute__((address_space(1))) void GV;
typedef __attribute__((address_space(3))) void LV;
#define GLOAD16(g, l) __builtin_amdgcn_global_load_lds((GV*)(g), (LV*)(l), 16, 0, 0)

__device__ __forceinline__ float b2f(u16 u) {
    union { float f; unsigned int i; } v; v.i = ((unsigned int)u) << 16; return v.f;
}
__device__ __forceinline__ u16 f2b(float f) {
    union { float f; unsigned int i; } v; v.f = f;
    unsigned int x = v.i;
    return (u16)((x + 0x7fffu + ((x >> 16) & 1u)) >> 16);
}
__device__ __forceinline__ unsigned int cvt_pk_bf16(float lo, float hi) {
    unsigned int d;
    asm("v_cvt_pk_bf16_f32 %0, %1, %2" : "=v"(d) : "v"(lo), "v"(hi));
    return d;
}
__device__ __forceinline__ float silu(float t) {
    return t * __builtin_amdgcn_rcpf(1.f + __expf(-t));
}

// ------------- K1a: 3-NN partial (256-pt chunks, dual 128-pt ILP chains)
__global__ void knn_part_kernel(const float* __restrict__ xyz1, const float* __restrict__ xyz2,
                                float2* __restrict__ cand) {
    __shared__ float4 spt[256];
    int b = blockIdx.z, ck = blockIdx.y, tid = threadIdx.x;
    const float* p2 = xyz2 + (size_t)b * 3 * 2048;
    int s0 = ck << 8;
    {
        int s = s0 + tid;
        float x = p2[s], y = p2[2048 + s], z = p2[4096 + s];
        spt[tid] = make_float4(x, y, z, (x * x + y * y) + z * z);
    }
    __syncthreads();
    int n = blockIdx.x * 256 + tid;
    const float* p1 = xyz1 + (size_t)b * 3 * 8192;
    float qx = p1[n], qy = p1[8192 + n], qz = p1[16384 + n];
    float qn = (qx * qx + qy * qy) + qz * qz;
    // chain A: s in [0,128); chain B: s in [128,256) — independent, interleaved
    float d0 = 3.4e38f, d1 = 3.4e38f, d2 = 3.4e38f;
    int i0 = 0, i1 = 0, i2 = 0;
    float e0 = 3.4e38f, e1 = 3.4e38f, e2 = 3.4e38f;
    int j0 = 0, j1 = 0, j2 = 0;
#pragma unroll 2
    for (int s = 0; s < 128; ++s) {
        float4 p = spt[s];
        float dot = (qx * p.x + qy * p.y) + qz * p.z;
        float d = (-2.f * dot + qn) + p.w;   // reference op order
        if (d < d2) {
            int gi = s0 + s;
            if (d < d1) {
                if (d < d0) { d2 = d1; i2 = i1; d1 = d0; i1 = i0; d0 = d; i0 = gi; }
                else        { d2 = d1; i2 = i1; d1 = d;  i1 = gi; }
            } else          { d2 = d;  i2 = gi; }
        }
        float4 pb = spt[128 + s];
        float dotb = (qx * pb.x + qy * pb.y) + qz * pb.z;
        float db = (-2.f * dotb + qn) + pb.w;
        if (db < e2) {
            int gj = s0 + 128 + s;
            if (db < e1) {
                if (db < e0) { e2 = e1; j2 = j1; e1 = e0; j1 = j0; e0 = db; j0 = gj; }
                else         { e2 = e1; j2 = j1; e1 = db; j1 = gj; }
            } else           { e2 = db; j2 = gj; }
        }
    }
    // merge chain B into chain A (B indices all larger: strict < keeps tie order)
    float eb[3] = {e0, e1, e2};
    int jb[3] = {j0, j1, j2};
#pragma unroll
    for (int k = 0; k < 3; ++k) {
        float d = eb[k];
        if (d < d2) {
            int gi = jb[k];
            if (d < d1) {
                if (d < d0) { d2 = d1; i2 = i1; d1 = d0; i1 = i0; d0 = d; i0 = gi; }
                else        { d2 = d1; i2 = i1; d1 = d;  i1 = gi; }
            } else          { d2 = d;  i2 = gi; }
        }
    }
    float2* c = cand + (((size_t)b * 8192 + n) * 8 + ck) * 3;
    c[0] = make_float2(d0, __int_as_float(i0));
    c[1] = make_float2(d1, __int_as_float(i1));
    c[2] = make_float2(d2, __int_as_float(i2));
}

// ------ K2a: per-batch transpose f32 [C][S] -> bf16 [S][dstStride] (cols c0..)
__global__ void tr_kernel(const float* __restrict__ src, u16* __restrict__ dst,
                          int C, int S, int dstStride) {
    __shared__ u16 tile[64][70];
    int b = blockIdx.z;
    int s0 = blockIdx.x * 64, c0 = blockIdx.y * 64;
    int tid = threadIdx.x, lane = tid & 63, wv = tid >> 6;
    const float* sp = src + ((size_t)b * C + c0) * S + s0;
    for (int c = wv; c < 64; c += 4)
        tile[lane][c] = f2b(sp[(size_t)c * S + lane]);
    __syncthreads();
    u16* dp = dst + ((size_t)b * S + s0) * dstStride + c0;
    int s = tid >> 5, cp = tid & 31;
#pragma unroll
    for (int k = 0; k < 8; ++k) {
        int r = s + k * 8;
        unsigned int v = *(const unsigned int*)&tile[r][cp * 2];
        *(unsigned int*)&dp[(size_t)r * dstStride + cp * 2] = v;
    }
}

// --- K2b: fused merge(24 cand) + interp into X0t cols 128..383 (quad/point)
__global__ void build_x0_kernel(const u16* __restrict__ p2t, const float2* __restrict__ cand,
                                u16* __restrict__ x0t) {
    int b = blockIdx.y;
    int n = blockIdx.x * 64 + (threadIdx.x >> 2);
    int q = threadIdx.x & 3;
    const float2* c = cand + ((size_t)b * 8192 + n) * 24;
    float d0 = 3.4e38f, d1 = 3.4e38f, d2 = 3.4e38f;
    int i0 = 0, i1 = 0, i2 = 0;
#pragma unroll
    for (int k = 0; k < 24; ++k) {
        float2 p = c[k];
        float d = p.x;
        if (d < d2) {
            int gi = __float_as_int(p.y);
            if (d < d1) {
                if (d < d0) { d2 = d1; i2 = i1; d1 = d0; i1 = i0; d0 = d; i0 = gi; }
                else        { d2 = d1; i2 = i1; d1 = d;  i1 = gi; }
            } else          { d2 = d;  i2 = gi; }
        }
    }
    float r0w = 1.f / (d0 + 1e-8f), r1w = 1.f / (d1 + 1e-8f), r2w = 1.f / (d2 + 1e-8f);
    float inv = 1.f / (r0w + r1w + r2w);
    float w0 = r0w * inv, w1 = r1w * inv, w2 = r2w * inv;
    const u16* r0 = p2t + ((size_t)b * 2048 + i0) * 256;
    const u16* r1 = p2t + ((size_t)b * 2048 + i1) * 256;
    const u16* r2 = p2t + ((size_t)b * 2048 + i2) * 256;
    u16* out = x0t + ((size_t)b * 8192 + n) * 384;
#pragma unroll
    for (int i = 0; i < 8; ++i) {
        int cc = (i * 4 + q) * 8;
        bf16x8 a0 = *(const bf16x8*)&r0[cc];
        bf16x8 a1 = *(const bf16x8*)&r1[cc];
        bf16x8 a2 = *(const bf16x8*)&r2[cc];
        u16 ovu[8] __attribute__((aligned(16)));
#pragma unroll
        for (int j = 0; j < 8; ++j) {
            float v = w0 * b2f((u16)a0[j]) + w1 * b2f((u16)a1[j]) + w2 * b2f((u16)a2[j]);
            ovu[j] = f2b(v);
        }
        *(uint4*)&out[128 + cc] = *(const uint4*)ovu;
    }
}

// --------------------------------- weight f32 -> bf16 (3 buffers, one launch)
__global__ void cvt3_kernel(const float* __restrict__ s0, u16* __restrict__ d0, int n0,
                            const float* __restrict__ s1, u16* __restrict__ d1, int n1,
                            const float* __restrict__ s2, u16* __restrict__ d2, int n2) {
    int i = blockIdx.x * 256 + threadIdx.x;
    if (i < n0) d0[i] = f2b(s0[i]);
    if (i < n1) d1[i] = f2b(s1[i]);
    if (i < n2) d2[i] = f2b(s2[i]);
}

// ------------------------------------- K5: FiLM params
__global__ void film_kernel(const float* __restrict__ t_emb, const float* __restrict__ c_emb,
                            const float* __restrict__ tw, const float* __restrict__ tb,
                            const float* __restrict__ cw, const float* __restrict__ cb,
                            float* __restrict__ film) {
    __shared__ float te[256], ce[256];
    int b = blockIdx.x, tid = threadIdx.x;
    te[tid] = t_emb[b * 256 + tid];
    ce[tid] = c_emb[b * 256 + tid];
    __syncthreads();
    int j = tid + blockIdx.y * 256;
    const float* twr = tw + (size_t)j * 256;
    const float* cwr = cw + (size_t)j * 256;
    float s = 0.f;
    for (int k = 0; k < 256; ++k) s += te[k] * twr[k] + ce[k] * cwr[k];
    s += tb[j] + cb[j];
    film[b * 512 + j] = s;
}

// -------- K3: plain GEMM, BM=128 x BN=256, BK=32; ring-3 + counted vmcnt.
__global__ __launch_bounds__(512, 4) void gemm_kernel(
        const u16* __restrict__ At, const u16* __restrict__ W, const float* __restrict__ bias,
        u16* __restrict__ Out, float* __restrict__ part,
        int K, int M, int gshift) {
    __shared__ u16 lA[3][128 * 32];
    __shared__ u16 lB[3][256 * 32];
    __shared__ float bpart[8][2];
    int b = blockIdx.z;
    int n0 = blockIdx.x * 128, oBase = blockIdx.y << 8;
    int tid = threadIdx.x, lane = tid & 63, wv = tid >> 6;
    int wn = wv & 1, wo = wv >> 1;
    if (tid < 16) ((float*)bpart)[tid] = 0.f;
    f32x4 acc[4][4];
#pragma unroll
    for (int i = 0; i < 4; i++)
#pragma unroll
        for (int j = 0; j < 4; j++) acc[i][j] = (f32x4){0.f, 0.f, 0.f, 0.f};

    int row = tid >> 2;
    int csrc = ((tid & 3) ^ ((row >> 1) & 3)) * 8;
    const u16* aP = At + ((size_t)b * 8192 + n0 + row) * K + csrc;
    const u16* bP0 = W + ((size_t)(oBase + row)) * K + csrc;
    const u16* bP1 = W + ((size_t)(oBase + 128 + row)) * K + csrc;
    int nK = K >> 5;
    GLOAD16(aP, &lA[0][wv * 512]);
    GLOAD16(bP0, &lB[0][wv * 512]);
    GLOAD16(bP1, &lB[0][4096 + wv * 512]);
    aP += 32; bP0 += 32; bP1 += 32;
    if (nK > 1) {
        GLOAD16(aP, &lA[1][wv * 512]);
        GLOAD16(bP0, &lB[1][wv * 512]);
        GLOAD16(bP1, &lB[1][4096 + wv * 512]);
        aP += 32; bP0 += 32; bP1 += 32;
    }
    asm volatile("s_waitcnt lgkmcnt(0)" ::: "memory");
    int cur = 0, nx1 = 1, nx2 = 2;
    int cs = lane >> 4;
    for (int kt = 0; kt < nK; ++kt) {
        if (kt + 2 < nK) {
            GLOAD16(aP, &lA[nx2][wv * 512]);
            GLOAD16(bP0, &lB[nx2][wv * 512]);
            GLOAD16(bP1, &lB[nx2][4096 + wv * 512]);
            aP += 32; bP0 += 32; bP1 += 32;
            asm volatile("s_waitcnt vmcnt(6)" ::: "memory");
        } else if (kt + 1 < nK) {
            asm volatile("s_waitcnt vmcnt(3)" ::: "memory");
        } else {
            asm volatile("s_waitcnt vmcnt(0)" ::: "memory");
        }
        __builtin_amdgcn_s_barrier();
        const u16* la = lA[cur];
        const u16* lb = lB[cur];
        bf16x8 af[4], bfr[4];
#pragma unroll
        for (int mf = 0; mf < 4; mf++) {
            int R = wn * 64 + mf * 16 + (lane & 15);
            af[mf] = *(const bf16x8*)&la[R * 32 + ((cs ^ ((R >> 1) & 3)) * 8)];
        }
#pragma unroll
        for (int nf = 0; nf < 4; nf++) {
            int R = wo * 64 + nf * 16 + (lane & 15);
            bfr[nf] = *(const bf16x8*)&lb[R * 32 + ((cs ^ ((R >> 1) & 3)) * 8)];
        }
#pragma unroll
        for (int mf = 0; mf < 4; mf++)
#pragma unroll
            for (int nf = 0; nf < 4; nf++)
                acc[mf][nf] = __builtin_amdgcn_mfma_f32_16x16x32_bf16(bfr[nf], af[mf], acc[mf][nf], 0, 0, 0);
        __builtin_amdgcn_s_barrier();
        int t = cur; cur = nx1; nx1 = nx2; nx2 = t;
    }
    int oq = (lane >> 4) * 4;
    float4 bs[4];
    float s1[4] = {0.f, 0.f, 0.f, 0.f}, s2[4] = {0.f, 0.f, 0.f, 0.f};
#pragma unroll
    for (int nf = 0; nf < 4; nf++) bs[nf] = *(const float4*)&bias[oBase + wo * 64 + nf * 16 + oq];
#pragma unroll
    for (int mf = 0; mf < 4; mf++) {
        int n = n0 + wn * 64 + mf * 16 + (lane & 15);
        u16* rowp = Out + ((size_t)b * 8192 + n) * M + oBase + wo * 64 + oq;
#pragma unroll
        for (int nf = 0; nf < 4; nf++) {
            float v0 = acc[mf][nf][0] + bs[nf].x;
            float v1 = acc[mf][nf][1] + bs[nf].y;
            float v2 = acc[mf][nf][2] + bs[nf].z;
            float v3 = acc[mf][nf][3] + bs[nf].w;
            s1[nf] += (v0 + v1) + (v2 + v3);
            s2[nf] += (v0 * v0 + v1 * v1) + (v2 * v2 + v3 * v3);
            uint2 pk;
            pk.x = cvt_pk_bf16(v0, v1);
            pk.y = cvt_pk_bf16(v2, v3);
            *(uint2*)&rowp[nf * 16] = pk;
        }
    }
#pragma unroll
    for (int nf = 0; nf < 4; nf++) {
        float a = s1[nf], c = s2[nf];
#pragma unroll
        for (int off = 32; off > 0; off >>= 1) {
            a += __shfl_xor(a, off, 64);
            c += __shfl_xor(c, off, 64);
        }
        if (lane == 0) {
            int gl = (wo * 64 + nf * 16) >> gshift;
            atomicAdd(&bpart[gl][0], a);
            atomicAdd(&bpart[gl][1], c);
        }
    }
    __syncthreads();
    int nlg = 256 >> gshift;
    if (tid < 2 * nlg) {
        int gl = tid >> 1, s = tid & 1;
        int g = (oBase >> gshift) + gl;
        part[(((size_t)b * 8 + g) * 2 + s) * 64 + blockIdx.x] = bpart[gl][s];
    }
}

// ---- K3gn: BM=128 x BN=256, fused GN+SiLU on A (reg-staged, regular loads)
__global__ __launch_bounds__(512, 4) void gemm_gn_kernel(
        const u16* __restrict__ At, const u16* __restrict__ W, const float* __restrict__ bias,
        const float* __restrict__ tab,   // [2][8][K]
        u16* __restrict__ Out, float* __restrict__ part,
        int K, int M, int gshift) {
    __shared__ u16 lA[2][128 * 32];
    __shared__ u16 lB[2][256 * 32];
    __shared__ float cA[1024], cB[1024];
    __shared__ float bpart[8][2];
    int b = blockIdx.z;
    int n0 = blockIdx.x * 128, oBase = blockIdx.y << 8;
    int tid = threadIdx.x, lane = tid & 63, wv = tid >> 6;
    int wn = wv & 1, wo = wv >> 1;
    if (tid < 16) ((float*)bpart)[tid] = 0.f;
    f32x4 acc[4][4];
#pragma unroll
    for (int i = 0; i < 4; i++)
#pragma unroll
        for (int j = 0; j < 4; j++) acc[i][j] = (f32x4){0.f, 0.f, 0.f, 0.f};

    int row = tid >> 2;
    int csrc = ((tid & 3) ^ ((row >> 1) & 3)) * 8;
    const u16* aP = At + ((size_t)b * 8192 + n0 + row) * K + csrc;
    const u16* bP0 = W + ((size_t)(oBase + row)) * K + csrc;
    const u16* bP1 = W + ((size_t)(oBase + 128 + row)) * K + csrc;
    int nK = K >> 5;
    uint4 areg = *(const uint4*)aP; aP += 32;
    GLOAD16(bP0, &lB[0][wv * 512]);
    GLOAD16(bP1, &lB[0][4096 + wv * 512]);
    bP0 += 32; bP1 += 32;
    {
        const float* tA = tab + (size_t)b * K;
        const float* tB = tab + (size_t)(8 + b) * K;
        for (int i = tid; i < K; i += 512) { cA[i] = tA[i]; cB[i] = tB[i]; }
    }
    __syncthreads();   // coefs visible
    {
        int c = csrc;
        const u16* rr = (const u16*)&areg;
        float4 a0 = *(const float4*)&cA[c], a1 = *(const float4*)&cA[c + 4];
        float4 b0 = *(const float4*)&cB[c], b1 = *(const float4*)&cB[c + 4];
        float va[8] = {a0.x, a0.y, a0.z, a0.w, a1.x, a1.y, a1.z, a1.w};
        float vb[8] = {b0.x, b0.y, b0.z, b0.w, b1.x, b1.y, b1.z, b1.w};
        float v[8];
#pragma unroll
        for (int j = 0; j < 8; ++j) v[j] = silu(b2f(rr[j]) * va[j] + vb[j]);
        uint4 o;
        o.x = cvt_pk_bf16(v[0], v[1]); o.y = cvt_pk_bf16(v[2], v[3]);
        o.z = cvt_pk_bf16(v[4], v[5]); o.w = cvt_pk_bf16(v[6], v[7]);
        *(uint4*)&lA[0][tid * 8] = o;
    }
    asm volatile("s_waitcnt vmcnt(0) lgkmcnt(0)" ::: "memory");
    __builtin_amdgcn_s_barrier();
    int cur = 0;
    int cs = lane >> 4;
    for (int kt = 0; kt < nK; ++kt) {
        if (kt + 1 < nK) {
            areg = *(const uint4*)aP; aP += 32;
            GLOAD16(bP0, &lB[cur ^ 1][wv * 512]);
            GLOAD16(bP1, &lB[cur ^ 1][4096 + wv * 512]);
            bP0 += 32; bP1 += 32;
        }
        const u16* la = lA[cur];
        const u16* lb = lB[cur];
        bf16x8 af[4], bfr[4];
#pragma unroll
        for (int mf = 0; mf < 4; mf++) {
            int R = wn * 64 + mf * 16 + (lane & 15);
            af[mf] = *(const bf16x8*)&la[R * 32 + ((cs ^ ((R >> 1) & 3)) * 8)];
        }
#pragma unroll
        for (int nf = 0; nf < 4; nf++) {
            int R = wo * 64 + nf * 16 + (lane & 15);
            bfr[nf] = *(const bf16x8*)&lb[R * 32 + ((cs ^ ((R >> 1) & 3)) * 8)];
        }
#pragma unroll
        for (int mf = 0; mf < 4; mf++)
#pragma unroll
            for (int nf = 0; nf < 4; nf++)
                acc[mf][nf] = __builtin_amdgcn_mfma_f32_16x16x32_bf16(bfr[nf], af[mf], acc[mf][nf], 0, 0, 0);
        if (kt + 1 < nK) {
            int c = (kt + 1) * 32 + csrc;
            const u16* rr = (const u16*)&areg;
            float4 a0 = *(const float4*)&cA[c], a1 = *(const float4*)&cA[c + 4];
            float4 b0 = *(const float4*)&cB[c], b1 = *(const float4*)&cB[c + 4];
            float va[8] = {a0.x, a0.y, a0.z, a0.w, a1.x, a1.y, a1.z, a1.w};
            float vb[8] = {b0.x, b0.y, b0.z, b0.w, b1.x, b1.y, b1.z, b1.w};
            float v[8];
#pragma unroll
            for (int j = 0; j < 8; ++j) v[j] = silu(b2f(rr[j]) * va[j] + vb[j]);
            uint4 o;
            o.x = cvt_pk_bf16(v[0], v[1]); o.y = cvt_pk_bf16(v[2], v[3]);
            o.z = cvt_pk_bf16(v[4], v[5]); o.w = cvt_pk_bf16(v[6], v[7]);
            *(uint4*)&lA[cur ^ 1][tid * 8] = o;
            asm volatile("s_waitcnt vmcnt(0)" ::: "memory");
        }
        asm volatile("s_waitcnt lgkmcnt(0)" ::: "memory");
        __builtin_amdgcn_s_barrier();
        cur ^= 1;
    }
    int oq = (lane >> 4) * 4;
    float4 bs[4];
    float s1[4] = {0.f, 0.f, 0.f, 0.f}, s2[4] = {0.f, 0.f, 0.f, 0.f};
#pragma unroll
    for (int nf = 0; nf < 4; nf++) bs[nf] = *(const float4*)&bias[oBase + wo * 64 + nf * 16 + oq];
#pragma unroll
    for (int mf = 0; mf < 4; mf++) {
        int n = n0 + wn * 64 + mf * 16 + (lane & 15);
        u16* rowp = Out + ((size_t)b * 8192 + n) * M + oBase + wo * 64 + oq;
#pragma unroll
        for (int nf = 0; nf < 4; nf++) {
            float v0 = acc[mf][nf][0] + bs[nf].x;
            float v1 = acc[mf][nf][1] + bs[nf].y;
            float v2 = acc[mf][nf][2] + bs[nf].z;
            float v3 = acc[mf][nf][3] + bs[nf].w;
            s1[nf] += (v0 + v1) + (v2 + v3);
            s2[nf] += (v0 * v0 + v1 * v1) + (v2 * v2 + v3 * v3);
            uint2 pk;
            pk.x = cvt_pk_bf16(v0, v1);
            pk.y = cvt_pk_bf16(v2, v3);
            *(uint2*)&rowp[nf * 16] = pk;
        }
    }
#pragma unroll
    for (int nf = 0; nf < 4; nf++) {
        float a = s1[nf], c = s2[nf];
#pragma unroll
        for (int off = 32; off > 0; off >>= 1) {
            a += __shfl_xor(a, off, 64);
            c += __shfl_xor(c, off, 64);
        }
        if (lane == 0) {
            int gl = (wo * 64 + nf * 16) >> gshift;
            atomicAdd(&bpart[gl][0], a);
            atomicAdd(&bpart[gl][1], c);
        }
    }
    __syncthreads();
    int nlg = 256 >> gshift;
    if (tid < 2 * nlg) {
        int gl = tid >> 1, s = tid & 1;
        int g = (oBase >> gshift) + gl;
        part[(((size_t)b * 8 + g) * 2 + s) * 64 + blockIdx.x] = bpart[gl][s];
    }
}

// -------------- K3b: fused stats-reduce + coef build
__global__ void gn_stats_coef_kernel(const float* __restrict__ part,
                                     const float* __restrict__ gw, const float* __restrict__ gb,
                                     float* __restrict__ stats, float* __restrict__ tab,
                                     int K, int gshift, float invCnt) {
    __shared__ float sg[16];
    int b = blockIdx.y, c0 = blockIdx.x * 256, tid = threadIdx.x;
    int ng = 256 >> gshift;
    if (tid < 2 * ng) {
        int gl = tid >> 1, s = tid & 1;
        int g = (c0 >> gshift) + gl;
        const float* p = part + (((size_t)b * 8 + g) * 2 + s) * 64;
        float sum = 0.f;
#pragma unroll
        for (int i = 0; i < 64; i += 4) {
            float4 v = *(const float4*)&p[i];
            sum += (v.x + v.y) + (v.z + v.w);
        }
        sg[gl * 2 + s] = sum;
        stats[((size_t)b * 8 + g) * 2 + s] = sum;
    }
    __syncthreads();
    int c = c0 + tid;
    int gl = tid >> gshift;
    float sum = sg[gl * 2], ssq = sg[gl * 2 + 1];
    float m = sum * invCnt;
    float rstd = rsqrtf(fmaxf(ssq * invCnt - m * m, 0.f) + 1e-5f);
    float A = rstd * gw[c];
    tab[(size_t)b * K + c] = A;
    tab[(size_t)(8 + b) * K + c] = gb[c] - m * A;
}

// ------------------------------------- K3b': stats-only reduce (stage 3)
__global__ void gn_reduce_kernel(const float* __restrict__ part, float* __restrict__ stats) {
    int t = threadIdx.x;
    const float4* p = (const float4*)(part + (size_t)t * 64);
    float s = 0.f;
#pragma unroll
    for (int i = 0; i < 16; i++) { float4 v = p[i]; s += (v.x + v.y) + (v.z + v.w); }
    stats[t] = s;
}

// ------------- K4: out-of-place GN+SiLU apply (coefs from tab), C=256
__global__ void gn_apply_kernel(const u16* __restrict__ Yin, u16* __restrict__ Yout,
                                const float* __restrict__ tab) {
    int t = blockIdx.x * 256 + threadIdx.x;
    int c8 = t & 31, c0 = c8 << 3;
    int row0 = t >> 5;
    int rowstep = (gridDim.x * 256) >> 5;
    float A[8], Bc[8];
    int bprev = -1;
    for (int row = row0; row < 65536; row += rowstep) {
        int b = row >> 13;
        if (b != bprev) {
            bprev = b;
            float4 a0 = *(const float4*)(tab + (size_t)b * 256 + c0);
            float4 a1 = *(const float4*)(tab + (size_t)b * 256 + c0 + 4);
            float4 b0 = *(const float4*)(tab + (size_t)(8 + b) * 256 + c0);
            float4 b1 = *(const float4*)(tab + (size_t)(8 + b) * 256 + c0 + 4);
            A[0]=a0.x;A[1]=a0.y;A[2]=a0.z;A[3]=a0.w;A[4]=a1.x;A[5]=a1.y;A[6]=a1.z;A[7]=a1.w;
            Bc[0]=b0.x;Bc[1]=b0.y;Bc[2]=b0.z;Bc[3]=b0.w;Bc[4]=b1.x;Bc[5]=b1.y;Bc[6]=b1.z;Bc[7]=b1.w;
        }
        size_t off = ((size_t)row << 8) + c0;
        uint4 v4 = *(const uint4*)(Yin + off);
        const u16* vu = (const u16*)&v4;
        float v[8];
#pragma unroll
        for (int j = 0; j < 8; j++) v[j] = silu(b2f(vu[j]) * A[j] + Bc[j]);
        uint4 o;
        o.x = cvt_pk_bf16(v[0], v[1]); o.y = cvt_pk_bf16(v[2], v[3]);
        o.z = cvt_pk_bf16(v[4], v[5]); o.w = cvt_pk_bf16(v[6], v[7]);
        *(uint4*)(Yout + off) = o;
    }
}

// ------- K6: GN2 + FiLM + residual; full-line (64B/row) output stores
__global__ void final_kernel(const u16* __restrict__ Y2, const u16* __restrict__ Xraw,
                             const float* __restrict__ g0w, const float* __restrict__ g0b,
                             const float* __restrict__ stats0,
                             const float* __restrict__ g2w, const float* __restrict__ g2b,
                             const float* __restrict__ stats2, const float* __restrict__ film,
                             float* __restrict__ out) {
    __shared__ float tile[64][257];
    int b = blockIdx.y, n0 = blockIdx.x * 64, tid = threadIdx.x;
    const float invCnt = 1.f / (32.f * 8192.f);
    int c8 = tid & 31, c0 = c8 << 3, g = c8 >> 2;
    float sum = stats2[(b * 8 + g) * 2], ssq = stats2[(b * 8 + g) * 2 + 1];
    float m = sum * invCnt, rstd = rsqrtf(fmaxf(ssq * invCnt - m * m, 0.f) + 1e-5f);
    float sum0 = stats0[(b * 8 + g) * 2], ssq0 = stats0[(b * 8 + g) * 2 + 1];
    float m0 = sum0 * invCnt, rstd0 = rsqrtf(fmaxf(ssq0 * invCnt - m0 * m0, 0.f) + 1e-5f);
    float4 w0 = *(const float4*)(g2w + c0), w1 = *(const float4*)(g2w + c0 + 4);
    float4 q0 = *(const float4*)(g2b + c0), q1 = *(const float4*)(g2b + c0 + 4);
    float4 f0 = *(const float4*)(film + b * 512 + c0), f1 = *(const float4*)(film + b * 512 + c0 + 4);
    float4 h0 = *(const float4*)(film + b * 512 + 256 + c0), h1 = *(const float4*)(film + b * 512 + 256 + c0 + 4);
    float4 u0 = *(const float4*)(g0w + c0), u1 = *(const float4*)(g0w + c0 + 4);
    float4 e0 = *(const float4*)(g0b + c0), e1 = *(const float4*)(g0b + c0 + 4);
    float wv[8] = {w0.x, w0.y, w0.z, w0.w, w1.x, w1.y, w1.z, w1.w};
    float qv[8] = {q0.x, q0.y, q0.z, q0.w, q1.x, q1.y, q1.z, q1.w};
    float fs[8] = {f0.x, f0.y, f0.z, f0.w, f1.x, f1.y, f1.z, f1.w};
    float fh[8] = {h0.x, h0.y, h0.z, h0.w, h1.x, h1.y, h1.z, h1.w};
    float uv[8] = {u0.x, u0.y, u0.z, u0.w, u1.x, u1.y, u1.z, u1.w};
    float ev[8] = {e0.x, e0.y, e0.z, e0.w, e1.x, e1.y, e1.z, e1.w};
    float A[8], Bc[8], A0[8], B0[8];
#pragma unroll
    for (int j = 0; j < 8; j++) {
        float sc = 1.f + fs[j];
        A[j] = rstd * wv[j] * sc;
        Bc[j] = (qv[j] - m * rstd * wv[j]) * sc + fh[j];
        A0[j] = rstd0 * uv[j];
        B0[j] = ev[j] - m0 * A0[j];
    }
    int nrb = tid >> 5;
#pragma unroll
    for (int k = 0; k < 8; k++) {
        int nr = nrb + k * 8;
        size_t base = ((size_t)b * 8192 + n0 + nr) * 256 + c0;
        uint4 yv = *(const uint4*)(Y2 + base);
        uint4 xv = *(const uint4*)(Xraw + base);
        const u16* yy = (const u16*)&yv;
        const u16* xx = (const u16*)&xv;
#pragma unroll
        for (int j = 0; j < 8; j++) {
            float x = silu(b2f(xx[j]) * A0[j] + B0[j]);
            tile[nr][c0 + j] = b2f(yy[j]) * A[j] + Bc[j] + x;
        }
    }
    __syncthreads();
    // writer: each thread emits 64B contiguous per row chunk (full lines)
    for (int q = tid; q < 256 * 4; q += 256) {
        int c = q >> 2, n16 = q & 3;
        float4* dst = (float4*)&out[((size_t)b * 256 + c) * 8192 + n0 + n16 * 16];
#pragma unroll
        for (int j = 0; j < 4; j++) {
            int n = n16 * 16 + j * 4;
            float4 o;
            o.x = tile[n + 0][c];
            o.y = tile[n + 1][c];
            o.z = tile[n + 2][c];
            o.w = tile[n + 3][c];
            dst[j] = o;
        }
    }
}

// ---------------------------------------------------------------------------
extern "C" void kernel_launch(void* const* d_in, const int* in_sizes, int n_in,
                              void* d_out, int out_size, void* d_ws, size_t ws_size,
                              hipStream_t stream) {
    const float* xyz1    = (const float*)d_in[0];
    const float* points1 = (const float*)d_in[1];
    const float* xyz2    = (const float*)d_in[2];
    const float* points2 = (const float*)d_in[3];
    const float* t_emb   = (const float*)d_in[4];
    const float* c_emb   = (const float*)d_in[5];
    const float* mlp_w   = (const float*)d_in[6];
    const float* mlp_b   = (const float*)d_in[7];
    const float* mlp_gw  = (const float*)d_in[8];
    const float* mlp_gb  = (const float*)d_in[9];
    const float* c1w     = (const float*)d_in[10];
    const float* c1b     = (const float*)d_in[11];
    const float* g1w     = (const float*)d_in[12];
    const float* g1b     = (const float*)d_in[13];
    const float* c2w     = (const float*)d_in[14];
    const float* c2b     = (const float*)d_in[15];
    const float* g2w     = (const float*)d_in[16];
    const float* g2b     = (const float*)d_in[17];
    const float* tw      = (const float*)d_in[18];
    const float* tb      = (const float*)d_in[19];
    const float* cw      = (const float*)d_in[20];
    const float* cb      = (const float*)d_in[21];

    char* ws = (char*)d_ws;
    float* stats0 = (float*)(ws + 1572864);
    float* stats1 = (float*)(ws + 1573376);
    float* stats2 = (float*)(ws + 1573888);
    float* film   = (float*)(ws + 1574400);
    float* part0  = (float*)(ws + 1590784);
    float* part1  = (float*)(ws + 1623552);
    float* part2  = (float*)(ws + 1656320);
    u16* wb_mlp   = (u16*)(ws + 1689088);
    u16* wb_c1    = (u16*)(ws + 1885696);
    u16* wb_c2    = (u16*)(ws + 2409984);
    float* tab0   = (float*)(ws + 2934272);
    float* tab1   = (float*)(ws + 2950656);
    u16* X0t = (u16*)(ws + 4194304);               //  [B][N][384]
    u16* Y1t = (u16*)(ws + 54525952);              //  [B][N][256] raw conv1
    u16* H1t = (u16*)(ws + 88080384);              //  [B][N][1024] raw conv2
    u16* Y2t = X0t;
    u16* Y1act = X0t;
    u16* p2t = H1t;                                // dead until gemm2 writes H1t
    float2* cand = (float2*)(H1t + 8388608ull);    // 12.6 MB, same region, disjoint from p2t
    float* out = (float*)d_out;

    cvt3_kernel<<<1024, 256, 0, stream>>>(mlp_w, wb_mlp, 98304,
                                          c1w, wb_c1, 262144, c2w, wb_c2, 262144);
    knn_part_kernel<<<dim3(32, 8, 8), 256, 0, stream>>>(xyz1, xyz2, cand);
    tr_kernel<<<dim3(128, 2, 8), 256, 0, stream>>>(points1, X0t, 128, 8192, 384);
    tr_kernel<<<dim3(32, 4, 8), 256, 0, stream>>>(points2, p2t, 256, 2048, 256);
    build_x0_kernel<<<dim3(128, 8), 256, 0, stream>>>(p2t, cand, X0t);
    film_kernel<<<dim3(8, 2), 256, 0, stream>>>(t_emb, c_emb, tw, tb, cw, cb, film);
    // stage 1: conv(384->256)
    gemm_kernel<<<dim3(64, 1, 8), 512, 0, stream>>>(X0t, wb_mlp, mlp_b, Y1t, part0, 384, 256, 5);
    gn_stats_coef_kernel<<<dim3(1, 8), 256, 0, stream>>>(part0, mlp_gw, mlp_gb, stats0, tab0,
                                                         256, 5, 1.f / (32.f * 8192.f));
    gn_apply_kernel<<<512, 256, 0, stream>>>(Y1t, Y1act, tab0);
    // stage 2: conv(256->1024)
    gemm_kernel<<<dim3(64, 4, 8), 512, 0, stream>>>(Y1act, wb_c1, c1b, H1t, part1, 256, 1024, 7);
    gn_stats_coef_kernel<<<dim3(4, 8), 256, 0, stream>>>(part1, g1w, g1b, stats1, tab1,
                                                         1024, 7, 1.f / (128.f * 8192.f));
    // stage 3: conv(1024->256) fused GN1+SiLU on A
    gemm_gn_kernel<<<dim3(64, 1, 8), 512, 0, stream>>>(H1t, wb_c2, c2b, tab1, Y2t, part2, 1024, 256, 5);
    gn_reduce_kernel<<<1, 128, 0, stream>>>(part2, stats2);
    // final: GN2 + FiLM + residual (X from raw Y1 inline)
    final_kernel<<<dim3(128, 8), 256, 0, stream>>>(Y2t, Y1t, mlp_gw, mlp_gb, stats0,
                                                   g2w, g2b, stats2, film, out);
}

// Round 20
// 331.352 us; speedup vs baseline: 1.0121x; 1.0121x over previous
//
#include <hip/hip_runtime.h>
#include <hip/hip_bf16.h>

typedef unsigned short u16;
typedef __attribute__((ext_vector_type(4))) float f32x4;
typedef __attribute__((ext_vector_type(8))) short bf16x8;
typedef __attribute__((ext_vector_type(4))) unsigned int u32x4;

typedef const __attribute__((address_space(1))) void GV;
typedef __attribute__((address_space(3))) void LV;
#define GLOAD16(g, l) __builtin_amdgcn_global_load_lds((GV*)(g), (LV*)(l), 16, 0, 0)

__device__ __forceinline__ float b2f(u16 u) {
    union { float f; unsigned int i; } v; v.i = ((unsigned int)u) << 16; return v.f;
}
__device__ __forceinline__ u16 f2b(float f) {
    union { float f; unsigned int i; } v; v.f = f;
    unsigned int x = v.i;
    return (u16)((x + 0x7fffu + ((x >> 16) & 1u)) >> 16);
}
__device__ __forceinline__ unsigned int cvt_pk_bf16(float lo, float hi) {
    unsigned int d;
    asm("v_cvt_pk_bf16_f32 %0, %1, %2" : "=v"(d) : "v"(lo), "v"(hi));
    return d;
}
__device__ __forceinline__ float silu(float t) {
    return t * __builtin_amdgcn_rcpf(1.f + __expf(-t));
}

// ------------------------------------------ K1a: 3-NN partial (256-pt chunks)
__global__ void knn_part_kernel(const float* __restrict__ xyz1, const float* __restrict__ xyz2,
                                float2* __restrict__ cand) {
    __shared__ float4 spt[256];
    int b = blockIdx.z, ck = blockIdx.y, tid = threadIdx.x;
    const float* p2 = xyz2 + (size_t)b * 3 * 2048;
    int s0 = ck << 8;
    {
        int s = s0 + tid;
        float x = p2[s], y = p2[2048 + s], z = p2[4096 + s];
        spt[tid] = make_float4(x, y, z, (x * x + y * y) + z * z);
    }
    __syncthreads();
    int n = blockIdx.x * 256 + tid;
    const float* p1 = xyz1 + (size_t)b * 3 * 8192;
    float qx = p1[n], qy = p1[8192 + n], qz = p1[16384 + n];
    float qn = (qx * qx + qy * qy) + qz * qz;
    float d0 = 3.4e38f, d1 = 3.4e38f, d2 = 3.4e38f;
    int i0 = 0, i1 = 0, i2 = 0;
#pragma unroll 4
    for (int s = 0; s < 256; ++s) {
        float4 p = spt[s];
        float dot = (qx * p.x + qy * p.y) + qz * p.z;
        float d = (-2.f * dot + qn) + p.w;   // reference op order
        if (d < d2) {
            int gi = s0 + s;
            if (d < d1) {
                if (d < d0) { d2 = d1; i2 = i1; d1 = d0; i1 = i0; d0 = d; i0 = gi; }
                else        { d2 = d1; i2 = i1; d1 = d;  i1 = gi; }
            } else          { d2 = d;  i2 = gi; }
        }
    }
    float2* c = cand + (((size_t)b * 8192 + n) * 8 + ck) * 3;
    c[0] = make_float2(d0, __int_as_float(i0));
    c[1] = make_float2(d1, __int_as_float(i1));
    c[2] = make_float2(d2, __int_as_float(i2));
}

// ------ K2a: per-batch transpose f32 [C][S] -> bf16 [S][dstStride] (cols c0..)
__global__ void tr_kernel(const float* __restrict__ src, u16* __restrict__ dst,
                          int C, int S, int dstStride) {
    __shared__ u16 tile[64][70];
    int b = blockIdx.z;
    int s0 = blockIdx.x * 64, c0 = blockIdx.y * 64;
    int tid = threadIdx.x, lane = tid & 63, wv = tid >> 6;
    const float* sp = src + ((size_t)b * C + c0) * S + s0;
    for (int c = wv; c < 64; c += 4)
        tile[lane][c] = f2b(sp[(size_t)c * S + lane]);
    __syncthreads();
    u16* dp = dst + ((size_t)b * S + s0) * dstStride + c0;
    int s = tid >> 5, cp = tid & 31;
#pragma unroll
    for (int k = 0; k < 8; ++k) {
        int r = s + k * 8;
        unsigned int v = *(const unsigned int*)&tile[r][cp * 2];
        *(unsigned int*)&dp[(size_t)r * dstStride + cp * 2] = v;
    }
}

// --- K2b: fused merge(24 cand) + interp into X0t cols 128..383 (quad/point)
__global__ void build_x0_kernel(const u16* __restrict__ p2t, const float2* __restrict__ cand,
                                u16* __restrict__ x0t) {
    int b = blockIdx.y;
    int n = blockIdx.x * 64 + (threadIdx.x >> 2);
    int q = threadIdx.x & 3;
    const float2* c = cand + ((size_t)b * 8192 + n) * 24;
    float d0 = 3.4e38f, d1 = 3.4e38f, d2 = 3.4e38f;
    int i0 = 0, i1 = 0, i2 = 0;
#pragma unroll
    for (int k = 0; k < 24; ++k) {
        float2 p = c[k];
        float d = p.x;
        if (d < d2) {
            int gi = __float_as_int(p.y);
            if (d < d1) {
                if (d < d0) { d2 = d1; i2 = i1; d1 = d0; i1 = i0; d0 = d; i0 = gi; }
                else        { d2 = d1; i2 = i1; d1 = d;  i1 = gi; }
            } else          { d2 = d;  i2 = gi; }
        }
    }
    float r0w = 1.f / (d0 + 1e-8f), r1w = 1.f / (d1 + 1e-8f), r2w = 1.f / (d2 + 1e-8f);
    float inv = 1.f / (r0w + r1w + r2w);
    float w0 = r0w * inv, w1 = r1w * inv, w2 = r2w * inv;
    const u16* r0 = p2t + ((size_t)b * 2048 + i0) * 256;
    const u16* r1 = p2t + ((size_t)b * 2048 + i1) * 256;
    const u16* r2 = p2t + ((size_t)b * 2048 + i2) * 256;
    u16* out = x0t + ((size_t)b * 8192 + n) * 384;
#pragma unroll
    for (int i = 0; i < 8; ++i) {
        int cc = (i * 4 + q) * 8;
        bf16x8 a0 = *(const bf16x8*)&r0[cc];
        bf16x8 a1 = *(const bf16x8*)&r1[cc];
        bf16x8 a2 = *(const bf16x8*)&r2[cc];
        u16 ovu[8] __attribute__((aligned(16)));
#pragma unroll
        for (int j = 0; j < 8; ++j) {
            float v = w0 * b2f((u16)a0[j]) + w1 * b2f((u16)a1[j]) + w2 * b2f((u16)a2[j]);
            ovu[j] = f2b(v);
        }
        *(uint4*)&out[128 + cc] = *(const uint4*)ovu;
    }
}

// --------------------------------- weight f32 -> bf16 (3 buffers, one launch)
__global__ void cvt3_kernel(const float* __restrict__ s0, u16* __restrict__ d0, int n0,
                            const float* __restrict__ s1, u16* __restrict__ d1, int n1,
                            const float* __restrict__ s2, u16* __restrict__ d2, int n2) {
    int i = blockIdx.x * 256 + threadIdx.x;
    if (i < n0) d0[i] = f2b(s0[i]);
    if (i < n1) d1[i] = f2b(s1[i]);
    if (i < n2) d2[i] = f2b(s2[i]);
}

// ------------------------------------- K5: FiLM params
__global__ void film_kernel(const float* __restrict__ t_emb, const float* __restrict__ c_emb,
                            const float* __restrict__ tw, const float* __restrict__ tb,
                            const float* __restrict__ cw, const float* __restrict__ cb,
                            float* __restrict__ film) {
    __shared__ float te[256], ce[256];
    int b = blockIdx.x, tid = threadIdx.x;
    te[tid] = t_emb[b * 256 + tid];
    ce[tid] = c_emb[b * 256 + tid];
    __syncthreads();
    int j = tid + blockIdx.y * 256;
    const float* twr = tw + (size_t)j * 256;
    const float* cwr = cw + (size_t)j * 256;
    float s = 0.f;
    for (int k = 0; k < 256; ++k) s += te[k] * twr[k] + ce[k] * cwr[k];
    s += tb[j] + cb[j];
    film[b * 512 + j] = s;
}

// -------- K3: plain GEMM, BM=128 x BN=256, BK=32; ring-3 + counted vmcnt.
__global__ __launch_bounds__(512, 4) void gemm_kernel(
        const u16* __restrict__ At, const u16* __restrict__ W, const float* __restrict__ bias,
        u16* __restrict__ Out, float* __restrict__ part,
        int K, int M, int gshift) {
    __shared__ u16 lA[3][128 * 32];
    __shared__ u16 lB[3][256 * 32];
    __shared__ float bpart[8][2];
    int b = blockIdx.z;
    int n0 = blockIdx.x * 128, oBase = blockIdx.y << 8;
    int tid = threadIdx.x, lane = tid & 63, wv = tid >> 6;
    int wn = wv & 1, wo = wv >> 1;
    if (tid < 16) ((float*)bpart)[tid] = 0.f;
    f32x4 acc[4][4];
#pragma unroll
    for (int i = 0; i < 4; i++)
#pragma unroll
        for (int j = 0; j < 4; j++) acc[i][j] = (f32x4){0.f, 0.f, 0.f, 0.f};

    int row = tid >> 2;
    int csrc = ((tid & 3) ^ ((row >> 1) & 3)) * 8;
    const u16* aP = At + ((size_t)b * 8192 + n0 + row) * K + csrc;
    const u16* bP0 = W + ((size_t)(oBase + row)) * K + csrc;
    const u16* bP1 = W + ((size_t)(oBase + 128 + row)) * K + csrc;
    int nK = K >> 5;
    GLOAD16(aP, &lA[0][wv * 512]);
    GLOAD16(bP0, &lB[0][wv * 512]);
    GLOAD16(bP1, &lB[0][4096 + wv * 512]);
    aP += 32; bP0 += 32; bP1 += 32;
    if (nK > 1) {
        GLOAD16(aP, &lA[1][wv * 512]);
        GLOAD16(bP0, &lB[1][wv * 512]);
        GLOAD16(bP1, &lB[1][4096 + wv * 512]);
        aP += 32; bP0 += 32; bP1 += 32;
    }
    asm volatile("s_waitcnt lgkmcnt(0)" ::: "memory");
    int cur = 0, nx1 = 1, nx2 = 2;
    int cs = lane >> 4;
    for (int kt = 0; kt < nK; ++kt) {
        if (kt + 2 < nK) {
            GLOAD16(aP, &lA[nx2][wv * 512]);
            GLOAD16(bP0, &lB[nx2][wv * 512]);
            GLOAD16(bP1, &lB[nx2][4096 + wv * 512]);
            aP += 32; bP0 += 32; bP1 += 32;
            asm volatile("s_waitcnt vmcnt(6)" ::: "memory");
        } else if (kt + 1 < nK) {
            asm volatile("s_waitcnt vmcnt(3)" ::: "memory");
        } else {
            asm volatile("s_waitcnt vmcnt(0)" ::: "memory");
        }
        __builtin_amdgcn_s_barrier();
        const u16* la = lA[cur];
        const u16* lb = lB[cur];
        bf16x8 af[4], bfr[4];
#pragma unroll
        for (int mf = 0; mf < 4; mf++) {
            int R = wn * 64 + mf * 16 + (lane & 15);
            af[mf] = *(const bf16x8*)&la[R * 32 + ((cs ^ ((R >> 1) & 3)) * 8)];
        }
#pragma unroll
        for (int nf = 0; nf < 4; nf++) {
            int R = wo * 64 + nf * 16 + (lane & 15);
            bfr[nf] = *(const bf16x8*)&lb[R * 32 + ((cs ^ ((R >> 1) & 3)) * 8)];
        }
#pragma unroll
        for (int mf = 0; mf < 4; mf++)
#pragma unroll
            for (int nf = 0; nf < 4; nf++)
                acc[mf][nf] = __builtin_amdgcn_mfma_f32_16x16x32_bf16(bfr[nf], af[mf], acc[mf][nf], 0, 0, 0);
        __builtin_amdgcn_s_barrier();
        int t = cur; cur = nx1; nx1 = nx2; nx2 = t;
    }
    int oq = (lane >> 4) * 4;
    float4 bs[4];
    float s1[4] = {0.f, 0.f, 0.f, 0.f}, s2[4] = {0.f, 0.f, 0.f, 0.f};
#pragma unroll
    for (int nf = 0; nf < 4; nf++) bs[nf] = *(const float4*)&bias[oBase + wo * 64 + nf * 16 + oq];
#pragma unroll
    for (int mf = 0; mf < 4; mf++) {
        int n = n0 + wn * 64 + mf * 16 + (lane & 15);
        u16* rowp = Out + ((size_t)b * 8192 + n) * M + oBase + wo * 64 + oq;
#pragma unroll
        for (int nf = 0; nf < 4; nf++) {
            float v0 = acc[mf][nf][0] + bs[nf].x;
            float v1 = acc[mf][nf][1] + bs[nf].y;
            float v2 = acc[mf][nf][2] + bs[nf].z;
            float v3 = acc[mf][nf][3] + bs[nf].w;
            s1[nf] += (v0 + v1) + (v2 + v3);
            s2[nf] += (v0 * v0 + v1 * v1) + (v2 * v2 + v3 * v3);
            uint2 pk;
            pk.x = cvt_pk_bf16(v0, v1);
            pk.y = cvt_pk_bf16(v2, v3);
            *(uint2*)&rowp[nf * 16] = pk;
        }
    }
#pragma unroll
    for (int nf = 0; nf < 4; nf++) {
        float a = s1[nf], c = s2[nf];
#pragma unroll
        for (int off = 32; off > 0; off >>= 1) {
            a += __shfl_xor(a, off, 64);
            c += __shfl_xor(c, off, 64);
        }
        if (lane == 0) {
            int gl = (wo * 64 + nf * 16) >> gshift;
            atomicAdd(&bpart[gl][0], a);
            atomicAdd(&bpart[gl][1], c);
        }
    }
    __syncthreads();
    int nlg = 256 >> gshift;
    if (tid < 2 * nlg) {
        int gl = tid >> 1, s = tid & 1;
        int g = (oBase >> gshift) + gl;
        part[(((size_t)b * 8 + g) * 2 + s) * 64 + blockIdx.x] = bpart[gl][s];
    }
}

// ---- K3gn: BM=128 x BN=256, fused GN+SiLU on A (reg-staged, nt A loads)
__global__ __launch_bounds__(512, 4) void gemm_gn_kernel(
        const u16* __restrict__ At, const u16* __restrict__ W, const float* __restrict__ bias,
        const float* __restrict__ tab,   // [2][8][K]
        u16* __restrict__ Out, float* __restrict__ part,
        int K, int M, int gshift) {
    __shared__ u16 lA[2][128 * 32];
    __shared__ u16 lB[2][256 * 32];
    __shared__ float cA[1024], cB[1024];
    __shared__ float bpart[8][2];
    int b = blockIdx.z;
    int n0 = blockIdx.x * 128, oBase = blockIdx.y << 8;
    int tid = threadIdx.x, lane = tid & 63, wv = tid >> 6;
    int wn = wv & 1, wo = wv >> 1;
    if (tid < 16) ((float*)bpart)[tid] = 0.f;
    f32x4 acc[4][4];
#pragma unroll
    for (int i = 0; i < 4; i++)
#pragma unroll
        for (int j = 0; j < 4; j++) acc[i][j] = (f32x4){0.f, 0.f, 0.f, 0.f};

    int row = tid >> 2;
    int csrc = ((tid & 3) ^ ((row >> 1) & 3)) * 8;
    const u16* aP = At + ((size_t)b * 8192 + n0 + row) * K + csrc;
    const u16* bP0 = W + ((size_t)(oBase + row)) * K + csrc;
    const u16* bP1 = W + ((size_t)(oBase + 128 + row)) * K + csrc;
    int nK = K >> 5;
    u32x4 areg = __builtin_nontemporal_load((const u32x4*)aP); aP += 32;
    GLOAD16(bP0, &lB[0][wv * 512]);
    GLOAD16(bP1, &lB[0][4096 + wv * 512]);
    bP0 += 32; bP1 += 32;
    {
        const float* tA = tab + (size_t)b * K;
        const float* tB = tab + (size_t)(8 + b) * K;
        for (int i = tid; i < K; i += 512) { cA[i] = tA[i]; cB[i] = tB[i]; }
    }
    __syncthreads();   // coefs visible
    {
        int c = csrc;
        const u16* rr = (const u16*)&areg;
        float4 a0 = *(const float4*)&cA[c], a1 = *(const float4*)&cA[c + 4];
        float4 b0 = *(const float4*)&cB[c], b1 = *(const float4*)&cB[c + 4];
        float va[8] = {a0.x, a0.y, a0.z, a0.w, a1.x, a1.y, a1.z, a1.w};
        float vb[8] = {b0.x, b0.y, b0.z, b0.w, b1.x, b1.y, b1.z, b1.w};
        float v[8];
#pragma unroll
        for (int j = 0; j < 8; ++j) v[j] = silu(b2f(rr[j]) * va[j] + vb[j]);
        uint4 o;
        o.x = cvt_pk_bf16(v[0], v[1]); o.y = cvt_pk_bf16(v[2], v[3]);
        o.z = cvt_pk_bf16(v[4], v[5]); o.w = cvt_pk_bf16(v[6], v[7]);
        *(uint4*)&lA[0][tid * 8] = o;
    }
    asm volatile("s_waitcnt vmcnt(0) lgkmcnt(0)" ::: "memory");
    __builtin_amdgcn_s_barrier();
    int cur = 0;
    int cs = lane >> 4;
    for (int kt = 0; kt < nK; ++kt) {
        if (kt + 1 < nK) {
            areg = __builtin_nontemporal_load((const u32x4*)aP); aP += 32;
            GLOAD16(bP0, &lB[cur ^ 1][wv * 512]);
            GLOAD16(bP1, &lB[cur ^ 1][4096 + wv * 512]);
            bP0 += 32; bP1 += 32;
        }
        const u16* la = lA[cur];
        const u16* lb = lB[cur];
        bf16x8 af[4], bfr[4];
#pragma unroll
        for (int mf = 0; mf < 4; mf++) {
            int R = wn * 64 + mf * 16 + (lane & 15);
            af[mf] = *(const bf16x8*)&la[R * 32 + ((cs ^ ((R >> 1) & 3)) * 8)];
        }
#pragma unroll
        for (int nf = 0; nf < 4; nf++) {
            int R = wo * 64 + nf * 16 + (lane & 15);
            bfr[nf] = *(const bf16x8*)&lb[R * 32 + ((cs ^ ((R >> 1) & 3)) * 8)];
        }
#pragma unroll
        for (int mf = 0; mf < 4; mf++)
#pragma unroll
            for (int nf = 0; nf < 4; nf++)
                acc[mf][nf] = __builtin_amdgcn_mfma_f32_16x16x32_bf16(bfr[nf], af[mf], acc[mf][nf], 0, 0, 0);
        if (kt + 1 < nK) {
            int c = (kt + 1) * 32 + csrc;
            const u16* rr = (const u16*)&areg;
            float4 a0 = *(const float4*)&cA[c], a1 = *(const float4*)&cA[c + 4];
            float4 b0 = *(const float4*)&cB[c], b1 = *(const float4*)&cB[c + 4];
            float va[8] = {a0.x, a0.y, a0.z, a0.w, a1.x, a1.y, a1.z, a1.w};
            float vb[8] = {b0.x, b0.y, b0.z, b0.w, b1.x, b1.y, b1.z, b1.w};
            float v[8];
#pragma unroll
            for (int j = 0; j < 8; ++j) v[j] = silu(b2f(rr[j]) * va[j] + vb[j]);
            uint4 o;
            o.x = cvt_pk_bf16(v[0], v[1]); o.y = cvt_pk_bf16(v[2], v[3]);
            o.z = cvt_pk_bf16(v[4], v[5]); o.w = cvt_pk_bf16(v[6], v[7]);
            *(uint4*)&lA[cur ^ 1][tid * 8] = o;
            asm volatile("s_waitcnt vmcnt(0)" ::: "memory");
        }
        asm volatile("s_waitcnt lgkmcnt(0)" ::: "memory");
        __builtin_amdgcn_s_barrier();
        cur ^= 1;
    }
    int oq = (lane >> 4) * 4;
    float4 bs[4];
    float s1[4] = {0.f, 0.f, 0.f, 0.f}, s2[4] = {0.f, 0.f, 0.f, 0.f};
#pragma unroll
    for (int nf = 0; nf < 4; nf++) bs[nf] = *(const float4*)&bias[oBase + wo * 64 + nf * 16 + oq];
#pragma unroll
    for (int mf = 0; mf < 4; mf++) {
        int n = n0 + wn * 64 + mf * 16 + (lane & 15);
        u16* rowp = Out + ((size_t)b * 8192 + n) * M + oBase + wo * 64 + oq;
#pragma unroll
        for (int nf = 0; nf < 4; nf++) {
            float v0 = acc[mf][nf][0] + bs[nf].x;
            float v1 = acc[mf][nf][1] + bs[nf].y;
            float v2 = acc[mf][nf][2] + bs[nf].z;
            float v3 = acc[mf][nf][3] + bs[nf].w;
            s1[nf] += (v0 + v1) + (v2 + v3);
            s2[nf] += (v0 * v0 + v1 * v1) + (v2 * v2 + v3 * v3);
            uint2 pk;
            pk.x = cvt_pk_bf16(v0, v1);
            pk.y = cvt_pk_bf16(v2, v3);
            *(uint2*)&rowp[nf * 16] = pk;
        }
    }
#pragma unroll
    for (int nf = 0; nf < 4; nf++) {
        float a = s1[nf], c = s2[nf];
#pragma unroll
        for (int off = 32; off > 0; off >>= 1) {
            a += __shfl_xor(a, off, 64);
            c += __shfl_xor(c, off, 64);
        }
        if (lane == 0) {
            int gl = (wo * 64 + nf * 16) >> gshift;
            atomicAdd(&bpart[gl][0], a);
            atomicAdd(&bpart[gl][1], c);
        }
    }
    __syncthreads();
    int nlg = 256 >> gshift;
    if (tid < 2 * nlg) {
        int gl = tid >> 1, s = tid & 1;
        int g = (oBase >> gshift) + gl;
        part[(((size_t)b * 8 + g) * 2 + s) * 64 + blockIdx.x] = bpart[gl][s];
    }
}

// -------------- K3b: fused stats-reduce + coef build
__global__ void gn_stats_coef_kernel(const float* __restrict__ part,
                                     const float* __restrict__ gw, const float* __restrict__ gb,
                                     float* __restrict__ stats, float* __restrict__ tab,
                                     int K, int gshift, float invCnt) {
    __shared__ float sg[16];
    int b = blockIdx.y, c0 = blockIdx.x * 256, tid = threadIdx.x;
    int ng = 256 >> gshift;
    if (tid < 2 * ng) {
        int gl = tid >> 1, s = tid & 1;
        int g = (c0 >> gshift) + gl;
        const float* p = part + (((size_t)b * 8 + g) * 2 + s) * 64;
        float sum = 0.f;
#pragma unroll
        for (int i = 0; i < 64; i += 4) {
            float4 v = *(const float4*)&p[i];
            sum += (v.x + v.y) + (v.z + v.w);
        }
        sg[gl * 2 + s] = sum;
        stats[((size_t)b * 8 + g) * 2 + s] = sum;
    }
    __syncthreads();
    int c = c0 + tid;
    int gl = tid >> gshift;
    float sum = sg[gl * 2], ssq = sg[gl * 2 + 1];
    float m = sum * invCnt;
    float rstd = rsqrtf(fmaxf(ssq * invCnt - m * m, 0.f) + 1e-5f);
    float A = rstd * gw[c];
    tab[(size_t)b * K + c] = A;
    tab[(size_t)(8 + b) * K + c] = gb[c] - m * A;
}

// ------------------------------------- K3b': stats-only reduce (stage 3)
__global__ void gn_reduce_kernel(const float* __restrict__ part, float* __restrict__ stats) {
    int t = threadIdx.x;
    const float4* p = (const float4*)(part + (size_t)t * 64);
    float s = 0.f;
#pragma unroll
    for (int i = 0; i < 16; i++) { float4 v = p[i]; s += (v.x + v.y) + (v.z + v.w); }
    stats[t] = s;
}

// ------------- K4: out-of-place GN+SiLU apply (coefs from tab), C=256
__global__ void gn_apply_kernel(const u16* __restrict__ Yin, u16* __restrict__ Yout,
                                const float* __restrict__ tab) {
    int t = blockIdx.x * 256 + threadIdx.x;
    int c8 = t & 31, c0 = c8 << 3;
    int row0 = t >> 5;
    int rowstep = (gridDim.x * 256) >> 5;
    float A[8], Bc[8];
    int bprev = -1;
    for (int row = row0; row < 65536; row += rowstep) {
        int b = row >> 13;
        if (b != bprev) {
            bprev = b;
            float4 a0 = *(const float4*)(tab + (size_t)b * 256 + c0);
            float4 a1 = *(const float4*)(tab + (size_t)b * 256 + c0 + 4);
            float4 b0 = *(const float4*)(tab + (size_t)(8 + b) * 256 + c0);
            float4 b1 = *(const float4*)(tab + (size_t)(8 + b) * 256 + c0 + 4);
            A[0]=a0.x;A[1]=a0.y;A[2]=a0.z;A[3]=a0.w;A[4]=a1.x;A[5]=a1.y;A[6]=a1.z;A[7]=a1.w;
            Bc[0]=b0.x;Bc[1]=b0.y;Bc[2]=b0.z;Bc[3]=b0.w;Bc[4]=b1.x;Bc[5]=b1.y;Bc[6]=b1.z;Bc[7]=b1.w;
        }
        size_t off = ((size_t)row << 8) + c0;
        uint4 v4 = *(const uint4*)(Yin + off);
        const u16* vu = (const u16*)&v4;
        float v[8];
#pragma unroll
        for (int j = 0; j < 8; j++) v[j] = silu(b2f(vu[j]) * A[j] + Bc[j]);
        uint4 o;
        o.x = cvt_pk_bf16(v[0], v[1]); o.y = cvt_pk_bf16(v[2], v[3]);
        o.z = cvt_pk_bf16(v[4], v[5]); o.w = cvt_pk_bf16(v[6], v[7]);
        *(uint4*)(Yout + off) = o;
    }
}

// ------- K6: GN2 + FiLM + residual; full-line (64B/row) output stores
__global__ void final_kernel(const u16* __restrict__ Y2, const u16* __restrict__ Xraw,
                             const float* __restrict__ g0w, const float* __restrict__ g0b,
                             const float* __restrict__ stats0,
                             const float* __restrict__ g2w, const float* __restrict__ g2b,
                             const float* __restrict__ stats2, const float* __restrict__ film,
                             float* __restrict__ out) {
    __shared__ float tile[64][257];
    int b = blockIdx.y, n0 = blockIdx.x * 64, tid = threadIdx.x;
    const float invCnt = 1.f / (32.f * 8192.f);
    int c8 = tid & 31, c0 = c8 << 3, g = c8 >> 2;
    float sum = stats2[(b * 8 + g) * 2], ssq = stats2[(b * 8 + g) * 2 + 1];
    float m = sum * invCnt, rstd = rsqrtf(fmaxf(ssq * invCnt - m * m, 0.f) + 1e-5f);
    float sum0 = stats0[(b * 8 + g) * 2], ssq0 = stats0[(b * 8 + g) * 2 + 1];
    float m0 = sum0 * invCnt, rstd0 = rsqrtf(fmaxf(ssq0 * invCnt - m0 * m0, 0.f) + 1e-5f);
    float4 w0 = *(const float4*)(g2w + c0), w1 = *(const float4*)(g2w + c0 + 4);
    float4 q0 = *(const float4*)(g2b + c0), q1 = *(const float4*)(g2b + c0 + 4);
    float4 f0 = *(const float4*)(film + b * 512 + c0), f1 = *(const float4*)(film + b * 512 + c0 + 4);
    float4 h0 = *(const float4*)(film + b * 512 + 256 + c0), h1 = *(const float4*)(film + b * 512 + 256 + c0 + 4);
    float4 u0 = *(const float4*)(g0w + c0), u1 = *(const float4*)(g0w + c0 + 4);
    float4 e0 = *(const float4*)(g0b + c0), e1 = *(const float4*)(g0b + c0 + 4);
    float wv[8] = {w0.x, w0.y, w0.z, w0.w, w1.x, w1.y, w1.z, w1.w};
    float qv[8] = {q0.x, q0.y, q0.z, q0.w, q1.x, q1.y, q1.z, q1.w};
    float fs[8] = {f0.x, f0.y, f0.z, f0.w, f1.x, f1.y, f1.z, f1.w};
    float fh[8] = {h0.x, h0.y, h0.z, h0.w, h1.x, h1.y, h1.z, h1.w};
    float uv[8] = {u0.x, u0.y, u0.z, u0.w, u1.x, u1.y, u1.z, u1.w};
    float ev[8] = {e0.x, e0.y, e0.z, e0.w, e1.x, e1.y, e1.z, e1.w};
    float A[8], Bc[8], A0[8], B0[8];
#pragma unroll
    for (int j = 0; j < 8; j++) {
        float sc = 1.f + fs[j];
        A[j] = rstd * wv[j] * sc;
        Bc[j] = (qv[j] - m * rstd * wv[j]) * sc + fh[j];
        A0[j] = rstd0 * uv[j];
        B0[j] = ev[j] - m0 * A0[j];
    }
    int nrb = tid >> 5;
#pragma unroll
    for (int k = 0; k < 8; k++) {
        int nr = nrb + k * 8;
        size_t base = ((size_t)b * 8192 + n0 + nr) * 256 + c0;
        uint4 yv = *(const uint4*)(Y2 + base);
        uint4 xv = *(const uint4*)(Xraw + base);
        const u16* yy = (const u16*)&yv;
        const u16* xx = (const u16*)&xv;
#pragma unroll
        for (int j = 0; j < 8; j++) {
            float x = silu(b2f(xx[j]) * A0[j] + B0[j]);
            tile[nr][c0 + j] = b2f(yy[j]) * A[j] + Bc[j] + x;
        }
    }
    __syncthreads();
    // writer: each thread emits 64B contiguous per row chunk (full lines)
    for (int q = tid; q < 256 * 4; q += 256) {
        int c = q >> 2, n16 = q & 3;
        float4* dst = (float4*)&out[((size_t)b * 256 + c) * 8192 + n0 + n16 * 16];
#pragma unroll
        for (int j = 0; j < 4; j++) {
            int n = n16 * 16 + j * 4;
            float4 o;
            o.x = tile[n + 0][c];
            o.y = tile[n + 1][c];
            o.z = tile[n + 2][c];
            o.w = tile[n + 3][c];
            dst[j] = o;
        }
    }
}

// ---------------------------------------------------------------------------
extern "C" void kernel_launch(void* const* d_in, const int* in_sizes, int n_in,
                              void* d_out, int out_size, void* d_ws, size_t ws_size,
                              hipStream_t stream) {
    const float* xyz1    = (const float*)d_in[0];
    const float* points1 = (const float*)d_in[1];
    const float* xyz2    = (const float*)d_in[2];
    const float* points2 = (const float*)d_in[3];
    const float* t_emb   = (const float*)d_in[4];
    const float* c_emb   = (const float*)d_in[5];
    const float* mlp_w   = (const float*)d_in[6];
    const float* mlp_b   = (const float*)d_in[7];
    const float* mlp_gw  = (const float*)d_in[8];
    const float* mlp_gb  = (const float*)d_in[9];
    const float* c1w     = (const float*)d_in[10];
    const float* c1b     = (const float*)d_in[11];
    const float* g1w     = (const float*)d_in[12];
    const float* g1b     = (const float*)d_in[13];
    const float* c2w     = (const float*)d_in[14];
    const float* c2b     = (const float*)d_in[15];
    const float* g2w     = (const float*)d_in[16];
    const float* g2b     = (const float*)d_in[17];
    const float* tw      = (const float*)d_in[18];
    const float* tb      = (const float*)d_in[19];
    const float* cw      = (const float*)d_in[20];
    const float* cb      = (const float*)d_in[21];

    char* ws = (char*)d_ws;
    float* stats0 = (float*)(ws + 1572864);
    float* stats1 = (float*)(ws + 1573376);
    float* stats2 = (float*)(ws + 1573888);
    float* film   = (float*)(ws + 1574400);
    float* part0  = (float*)(ws + 1590784);
    float* part1  = (float*)(ws + 1623552);
    float* part2  = (float*)(ws + 1656320);
    u16* wb_mlp   = (u16*)(ws + 1689088);
    u16* wb_c1    = (u16*)(ws + 1885696);
    u16* wb_c2    = (u16*)(ws + 2409984);
    float* tab0   = (float*)(ws + 2934272);
    float* tab1   = (float*)(ws + 2950656);
    u16* X0t = (u16*)(ws + 4194304);               //  [B][N][384]
    u16* Y1t = (u16*)(ws + 54525952);              //  [B][N][256] raw conv1
    u16* H1t = (u16*)(ws + 88080384);              //  [B][N][1024] raw conv2
    u16* Y2t = X0t;
    u16* Y1act = X0t;
    u16* p2t = H1t;                                // dead until gemm2 writes H1t
    float2* cand = (float2*)(H1t + 8388608ull);    // 12.6 MB, same region, disjoint from p2t
    float* out = (float*)d_out;

    cvt3_kernel<<<1024, 256, 0, stream>>>(mlp_w, wb_mlp, 98304,
                                          c1w, wb_c1, 262144, c2w, wb_c2, 262144);
    knn_part_kernel<<<dim3(32, 8, 8), 256, 0, stream>>>(xyz1, xyz2, cand);
    tr_kernel<<<dim3(128, 2, 8), 256, 0, stream>>>(points1, X0t, 128, 8192, 384);
    tr_kernel<<<dim3(32, 4, 8), 256, 0, stream>>>(points2, p2t, 256, 2048, 256);
    build_x0_kernel<<<dim3(128, 8), 256, 0, stream>>>(p2t, cand, X0t);
    film_kernel<<<dim3(8, 2), 256, 0, stream>>>(t_emb, c_emb, tw, tb, cw, cb, film);
    // stage 1: conv(384->256)
    gemm_kernel<<<dim3(64, 1, 8), 512, 0, stream>>>(X0t, wb_mlp, mlp_b, Y1t, part0, 384, 256, 5);
    gn_stats_coef_kernel<<<dim3(1, 8), 256, 0, stream>>>(part0, mlp_gw, mlp_gb, stats0, tab0,
                                                         256, 5, 1.f / (32.f * 8192.f));
    gn_apply_kernel<<<512, 256, 0, stream>>>(Y1t, Y1act, tab0);
    // stage 2: conv(256->1024)
    gemm_kernel<<<dim3(64, 4, 8), 512, 0, stream>>>(Y1act, wb_c1, c1b, H1t, part1, 256, 1024, 7);
    gn_stats_coef_kernel<<<dim3(4, 8), 256, 0, stream>>>(part1, g1w, g1b, stats1, tab1,
                                                         1024, 7, 1.f / (128.f * 8192.f));
    // stage 3: conv(1024->256) fused GN1+SiLU on A
    gemm_gn_kernel<<<dim3(64, 1, 8), 512, 0, stream>>>(H1t, wb_c2, c2b, tab1, Y2t, part2, 1024, 256, 5);
    gn_reduce_kernel<<<1, 128, 0, stream>>>(part2, stats2);
    // final: GN2 + FiLM + residual (X from raw Y1 inline)
    final_kernel<<<dim3(128, 8), 256, 0, stream>>>(Y2t, Y1t, mlp_gw, mlp_gb, stats0,
                                                   g2w, g2b, stats2, film, out);
}